// Round 10
// baseline (214.193 us; speedup 1.0000x reference)
//
#include <hip/hip_runtime.h>
#include <math.h>

#define SEQ   8192
#define DIM   2048
#define NH    16
#define DH    128
#define PD    512

static constexpr float LN_EPS = 1e-5f;
static constexpr float SCALE  = 0.08838834764831845f; // 1/sqrt(128)

typedef __bf16 bf16x8 __attribute__((ext_vector_type(8)));
typedef float  f32x4  __attribute__((ext_vector_type(4)));

// ---- workspace layout (floats); all offsets 16B aligned ----
static constexpr size_t OFF_QB   = 0;                      // 16
static constexpr size_t OFF_SMP  = 16;                     // 512 = smp[h][32]
static constexpr size_t OFF_QWB  = 528;                    // 16*2048 bf16 = 16384 floats
static constexpr size_t OFF_ELOG = 16912;                  // 8192*16 exp(logit), [s][h]
static constexpr size_t OFF_PCTX = OFF_ELOG + 131072;      // 64*16*2048 = 2097152
static constexpr size_t OFF_CTX  = OFF_PCTX + 2097152;     // 32768
static constexpr size_t OFF_X1   = OFF_CTX + 32768;        // 2048
static constexpr size_t OFF_H1R  = OFF_X1 + 2048;          // 512
static constexpr size_t OFF_X1F  = OFF_H1R + 512;          // 2048

// qWb[h][j] = bf16( q_h · W_k[:,j] ), qb[h] = q_h · b_k[h]; zero smp.
// grid 256 = (h 16) x (jc 16); 256 thr: col = t&127, k-half = t>>7
__global__ __launch_bounds__(256) void k_prep(const float* __restrict__ q,
                                              const float* __restrict__ Wkv,
                                              const float* __restrict__ bkv,
                                              __bf16* __restrict__ qWb,
                                              float* __restrict__ qb,
                                              float* __restrict__ smp) {
    int t = threadIdx.x;
    int h = blockIdx.x >> 4, jc = blockIdx.x & 15;
    int col = t & 127, kh = t >> 7;
    int j = jc * 128 + col;
    const float* w  = Wkv + (size_t)(h * DH + kh * 64) * DIM + j;
    const float* qh = q + h * DH + kh * 64;
    float acc = 0.f;
#pragma unroll 16
    for (int d = 0; d < 64; ++d)
        acc += qh[d] * __builtin_nontemporal_load(w + (size_t)d * DIM);
    __shared__ float part[128];
    if (kh) part[col] = acc;
    __syncthreads();
    if (!kh) qWb[h * DIM + j] = (__bf16)(acc + part[col]);
    if (jc == 0 && t < 64) {
        float p = q[h*DH + t] * bkv[h*DH + t] + q[h*DH + 64 + t] * bkv[h*DH + 64 + t];
        for (int off = 32; off; off >>= 1) p += __shfl_down(p, off);
        if (t == 0) qb[h] = p;
    }
    if (blockIdx.x == 0) { smp[t] = 0.f; smp[t + 256] = 0.f; }
}

// MFMA logits: elogT[s][h] = exp((x[s]·qW[h] + qb[h])*SCALE), partials -> smp.
// ROUND-10: back to the round-0-verified split kernel. 512 blocks (2/CU) --
// the isolated A/B on block count that rounds 3-9 (all 256-block, 38-47us)
// never provided. grid 512 (16 s-rows each), 256 thr = 4 waves = 4 K-quarters.
__global__ __launch_bounds__(256) void k_logits(const float* __restrict__ x,
                                                const __bf16* __restrict__ qWb,
                                                const float* __restrict__ qb,
                                                float* __restrict__ elogT,
                                                float* __restrict__ smp) {
    const int t = threadIdx.x;
    const int w = t >> 6, lane = t & 63;
    const int r = lane & 15, quad = lane >> 4;
    const int s0 = blockIdx.x * 16;
    __shared__ float dpart[4][64][4];
    __shared__ float hsum[NH];
    if (t < NH) hsum[t] = 0.f;

    const float*  xrow = x + (size_t)(s0 + r) * DIM + quad * 8;
    const __bf16* brow = qWb + r * DIM + quad * 8;  // r doubles as h for B operand
    const int kbase = w * 512;

    f32x4 acc = {0.f, 0.f, 0.f, 0.f};
#pragma unroll 4
    for (int i = 0; i < 16; ++i) {
        int k = kbase + i * 32;
        float4 xa = *(const float4*)(xrow + k);
        float4 xb = *(const float4*)(xrow + k + 4);
        bf16x8 af;
        af[0] = (__bf16)xa.x; af[1] = (__bf16)xa.y;
        af[2] = (__bf16)xa.z; af[3] = (__bf16)xa.w;
        af[4] = (__bf16)xb.x; af[5] = (__bf16)xb.y;
        af[6] = (__bf16)xb.z; af[7] = (__bf16)xb.w;
        bf16x8 bf = *(const bf16x8*)(brow + k);
        acc = __builtin_amdgcn_mfma_f32_16x16x32_bf16(af, bf, acc, 0, 0, 0);
    }
    dpart[w][lane][0] = acc[0];
    dpart[w][lane][1] = acc[1];
    dpart[w][lane][2] = acc[2];
    dpart[w][lane][3] = acc[3];
    __syncthreads();

    {   // t -> (lane2 = t&63, reg = t>>6); s_local = (lane2>>4)*4+reg, h = lane2&15
        const int lane2 = t & 63, reg = t >> 6;
        const int h = lane2 & 15, sl = (lane2 >> 4) * 4 + reg;
        float v = dpart[0][lane2][reg] + dpart[1][lane2][reg]
                + dpart[2][lane2][reg] + dpart[3][lane2][reg];
        float e = __expf((v + qb[h]) * SCALE);   // no max-sub: |logit| <~ 5
        elogT[(size_t)(s0 + sl) * NH + h] = e;
        atomicAdd(&hsum[h], e);
    }
    __syncthreads();
    if (t < NH) atomicAdd(&smp[t * 32 + (blockIdx.x & 31)], hsum[t]);
}

// Weighted ctx partials, col-sliced: pctx[sc][h][jc*256+t] =
//   sum_{128 rows of sc} elogT[s][h] * x[s][j].  x re-read is L3-HOT (just
// streamed by k_logits; nothing big written in between). Col-slicing (jc 0..7)
// decouples chunk count (64 -> pctx 8 MiB, was 32) from block count (512).
// High occupancy: ~50 VGPR, 8.2 KB LDS -> many blocks/CU, TLP hides latency.
__global__ __launch_bounds__(256) void k_wctx(const float* __restrict__ x,
                                              const float* __restrict__ elogT,
                                              float* __restrict__ pctx) {
    const int b = blockIdx.x, t = threadIdx.x;
    const int sc = b >> 3, jc = b & 7;
    const int s0 = sc * 128;
    const int j = jc * 256 + t;

    __shared__ float att[128 * NH];                 // 8 KB
    for (int i = t; i < 128 * NH; i += 256)
        att[i] = elogT[(size_t)s0 * NH + i];        // coalesced
    __syncthreads();

    float acc[NH];
#pragma unroll
    for (int h = 0; h < NH; ++h) acc[h] = 0.f;
    const float* xp = x + (size_t)s0 * DIM + j;
#pragma unroll 4
    for (int rr = 0; rr < 128; ++rr) {
        float xv = xp[(size_t)rr * DIM];
        const f32x4* ar = (const f32x4*)(att + rr * NH);   // LDS broadcast
        f32x4 a0 = ar[0], a1 = ar[1], a2 = ar[2], a3 = ar[3];
        float aa[NH];
        *(f32x4*)&aa[0] = a0; *(f32x4*)&aa[4]  = a1;
        *(f32x4*)&aa[8] = a2; *(f32x4*)&aa[12] = a3;
#pragma unroll
        for (int h = 0; h < NH; ++h) acc[h] += xv * aa[h];
    }
    // NT stores: pctx write-once/read-once; keep L2/L3 clean (x stays hot).
#pragma unroll
    for (int h = 0; h < NH; ++h)
        __builtin_nontemporal_store(acc[h],
            &pctx[((size_t)(sc * NH + h)) * DIM + j]);
}

// ctx[idx] = (sum_{c<64} pctx[c][idx]) / S[head(idx)]
// grid 512 x 256 thr: 64 outputs/block, 4-way chunk-split (16 each) + combine.
__global__ __launch_bounds__(256) void k_ctxred(const float* __restrict__ pctx,
                                                const float* __restrict__ smp,
                                                float* __restrict__ ctx) {
    const int b = blockIdx.x, t = threadIdx.x;
    const int h = b >> 5;                          // 32 blocks per head
    const int col = t & 63, ch = t >> 6;
    __shared__ float sInv;
    __shared__ float psum[4][64];
    const size_t idx = (size_t)b * 64 + col;
    float s = 0.f;
#pragma unroll
    for (int i = 0; i < 16; ++i)
        s += __builtin_nontemporal_load(
                 &pctx[(size_t)(ch * 16 + i) * (NH * DIM) + idx]);
    psum[ch][col] = s;
    if (t < 32) {
        float v = smp[h * 32 + t];
        for (int off = 16; off; off >>= 1) v += __shfl_xor(v, off);
        if (t == 0) sInv = 1.0f / v;
    }
    __syncthreads();
    if (ch == 0)
        ctx[idx] = (psum[0][col] + psum[1][col] + psum[2][col] + psum[3][col]) * sInv;
}

// x1[row] = ctx[row>>7]·W_v[row] + b_kv[DIM+row]; one wave/row, 4 rows/block
__global__ __launch_bounds__(256) void k_x1(const float* __restrict__ Wkv,
                                            const float* __restrict__ bkv,
                                            const float* __restrict__ ctx,
                                            float* __restrict__ x1) {
    int row = blockIdx.x * 4 + (threadIdx.x >> 6);
    int lane = threadIdx.x & 63;
    const float* w = Wkv + (size_t)(DIM + row) * DIM;
    const float* c = ctx + (row >> 7) * DIM;
    float acc = 0.f;
#pragma unroll
    for (int k = 0; k < 8; ++k) {
        int j = k * 256 + lane * 4;
        f32x4 wv = __builtin_nontemporal_load((const f32x4*)&w[j]);
        f32x4 cv = *(const f32x4*)&c[j];
        acc += wv[0]*cv[0] + wv[1]*cv[1] + wv[2]*cv[2] + wv[3]*cv[3];
    }
    for (int off = 32; off; off >>= 1) acc += __shfl_xor(acc, off);
    if (lane == 0) x1[row] = acc + bkv[DIM + row];
}

// h1raw[row] = x1·W_p1[row] + b_p1[row]
__global__ __launch_bounds__(256) void k_h1(const float* __restrict__ Wp1,
                                            const float* __restrict__ bp1,
                                            const float* __restrict__ x1,
                                            float* __restrict__ h1raw) {
    int row = blockIdx.x * 4 + (threadIdx.x >> 6);
    int lane = threadIdx.x & 63;
    const float* w = Wp1 + (size_t)row * DIM;
    float acc = 0.f;
#pragma unroll
    for (int k = 0; k < 8; ++k) {
        int j = k * 256 + lane * 4;
        f32x4 wv = __builtin_nontemporal_load((const f32x4*)&w[j]);
        f32x4 cv = *(const f32x4*)&x1[j];
        acc += wv[0]*cv[0] + wv[1]*cv[1] + wv[2]*cv[2] + wv[3]*cv[3];
    }
    for (int off = 32; off; off >>= 1) acc += __shfl_xor(acc, off);
    if (lane == 0) h1raw[row] = acc + bp1[row];
}

// Fused LN+relu+proj2: x1f[row] = relu(LN(h1raw))·W_p2[row] + b_p2[row]
__global__ __launch_bounds__(256) void k_x1f(const float* __restrict__ Wp2,
                                             const float* __restrict__ bp2,
                                             const float* __restrict__ h1raw,
                                             const float* __restrict__ lnw,
                                             const float* __restrict__ lnb,
                                             float* __restrict__ x1f) {
    int row = blockIdx.x * 4 + (threadIdx.x >> 6);
    int lane = threadIdx.x & 63;
    int j = lane * 8;
    float4 va = *(const float4*)&h1raw[j];
    float4 vb = *(const float4*)&h1raw[j + 4];
    float s = va.x + va.y + va.z + va.w + vb.x + vb.y + vb.z + vb.w;
    for (int off = 32; off; off >>= 1) s += __shfl_xor(s, off);
    float mu = s * (1.0f / PD);
    float dx[8];
    dx[0]=va.x-mu; dx[1]=va.y-mu; dx[2]=va.z-mu; dx[3]=va.w-mu;
    dx[4]=vb.x-mu; dx[5]=vb.y-mu; dx[6]=vb.z-mu; dx[7]=vb.w-mu;
    float s2 = 0.f;
#pragma unroll
    for (int i = 0; i < 8; ++i) s2 += dx[i] * dx[i];
    for (int off = 32; off; off >>= 1) s2 += __shfl_xor(s2, off);
    float rstd = rsqrtf(s2 * (1.0f / PD) + LN_EPS);
    float4 lw0 = *(const float4*)&lnw[j], lw1 = *(const float4*)&lnw[j + 4];
    float4 lb0 = *(const float4*)&lnb[j], lb1 = *(const float4*)&lnb[j + 4];
    float hln[8];
    hln[0]=fmaxf(dx[0]*rstd*lw0.x+lb0.x,0.f); hln[1]=fmaxf(dx[1]*rstd*lw0.y+lb0.y,0.f);
    hln[2]=fmaxf(dx[2]*rstd*lw0.z+lb0.z,0.f); hln[3]=fmaxf(dx[3]*rstd*lw0.w+lb0.w,0.f);
    hln[4]=fmaxf(dx[4]*rstd*lw1.x+lb1.x,0.f); hln[5]=fmaxf(dx[5]*rstd*lw1.y+lb1.y,0.f);
    hln[6]=fmaxf(dx[6]*rstd*lw1.z+lb1.z,0.f); hln[7]=fmaxf(dx[7]*rstd*lw1.w+lb1.w,0.f);
    const float* w = Wp2 + (size_t)row * PD + j;
    f32x4 w0 = __builtin_nontemporal_load((const f32x4*)w);
    f32x4 w1 = __builtin_nontemporal_load((const f32x4*)(w + 4));
    float acc = w0[0]*hln[0] + w0[1]*hln[1] + w0[2]*hln[2] + w0[3]*hln[3]
              + w1[0]*hln[4] + w1[1]*hln[5] + w1[2]*hln[6] + w1[3]*hln[7];
    for (int off = 32; off; off >>= 1) acc += __shfl_xor(acc, off);
    if (lane == 0) x1f[row] = acc + bp2[row];
}

// out[s][j] = x[s][j] + x1f[j]; 2 float4/thread, NT stores (write-once)
__global__ __launch_bounds__(256) void k_out(const float* __restrict__ x,
                                             const float* __restrict__ x1f,
                                             float* __restrict__ out) {
    size_t i = (size_t)blockIdx.x * 512 + threadIdx.x;
    f32x4 xv = ((const f32x4*)x)[i];
    f32x4 a  = ((const f32x4*)x1f)[(int)(i & 511)];
    __builtin_nontemporal_store(xv + a, (f32x4*)out + i);
    size_t i2 = i + 256;
    f32x4 xv2 = ((const f32x4*)x)[i2];
    f32x4 a2  = ((const f32x4*)x1f)[(int)(i2 & 511)];
    __builtin_nontemporal_store(xv2 + a2, (f32x4*)out + i2);
}

extern "C" void kernel_launch(void* const* d_in, const int* in_sizes, int n_in,
                              void* d_out, int out_size, void* d_ws, size_t ws_size,
                              hipStream_t stream) {
    const float* x    = (const float*)d_in[0];
    const float* q    = (const float*)d_in[1];
    const float* Wkv  = (const float*)d_in[2];
    const float* bkv  = (const float*)d_in[3];
    const float* Wp1  = (const float*)d_in[4];
    const float* bp1  = (const float*)d_in[5];
    const float* Wp2  = (const float*)d_in[6];
    const float* bp2  = (const float*)d_in[7];
    const float* lnw  = (const float*)d_in[8];
    const float* lnb  = (const float*)d_in[9];
    float* out = (float*)d_out;
    float* ws  = (float*)d_ws;

    float*  qb    = ws + OFF_QB;
    float*  smp   = ws + OFF_SMP;
    __bf16* qWb   = (__bf16*)(ws + OFF_QWB);
    float*  elogT = ws + OFF_ELOG;
    float*  pctx  = ws + OFF_PCTX;
    float*  ctx   = ws + OFF_CTX;
    float*  x1    = ws + OFF_X1;
    float*  h1raw = ws + OFF_H1R;
    float*  x1f   = ws + OFF_X1F;

    k_prep  <<<256, 256, 0, stream>>>(q, Wkv, bkv, qWb, qb, smp);
    k_logits<<<512, 256, 0, stream>>>(x, qWb, qb, elogT, smp);
    k_wctx  <<<512, 256, 0, stream>>>(x, elogT, pctx);
    k_ctxred<<<512, 256, 0, stream>>>(pctx, smp, ctx);
    k_x1    <<<512, 256, 0, stream>>>(Wkv, bkv, ctx, x1);
    k_h1    <<<128, 256, 0, stream>>>(Wp1, bp1, x1, h1raw);
    k_x1f   <<<512, 256, 0, stream>>>(Wp2, bp2, h1raw, lnw, lnb, x1f);
    k_out   <<<8192, 256, 0, stream>>>(x, x1f, out);
}